// Round 7
// baseline (1028.653 us; speedup 1.0000x reference)
//
#include <hip/hip_runtime.h>
#include <math.h>

#define BB 1024
#define CC 64
#define HH 32
#define VV 4096
#define NEL (BB*CC*HH)   // 2097152

#define RT 128        // rows per argmin block

typedef __attribute__((ext_vector_type(4))) float f32x4;
typedef __attribute__((ext_vector_type(8))) short bf16x8;   // 8 bf16 = 4 VGPRs

// ---------------- setup ----------------

__device__ double dev_cubic(double x){
#pragma clang fp contract(off)
  const double A = -0.75;
  x = fabs(x);
  if (x <= 1.0) return ((A + 2.0)*x - (A + 3.0))*x*x + 1.0;
  if (x < 2.0)  return A*(((x - 5.0)*x + 8.0)*x - 4.0);
  return 0.0;
}

__device__ __constant__ int c_vpatch[10] = {1,2,3,4,6,9,13,18,24,32};
__device__ __constant__ int c_pref[10]   = {0,1,3,6,10,16,25,38,56,80};

__global__ void gen_setup(float* Mdown, float* Mup, double* partial){
#pragma clang fp contract(off)
  int t = threadIdx.x;
  for (int i = t; i < 3584; i += 64) { Mdown[i] = 0.0f; Mup[i] = 0.0f; }
  if (t < 16) partial[t] = 0.0;
  __syncthreads();
  if (t < 20) {
    int si = t >> 1; int up = t & 1;
    int pn = c_vpatch[si];
    if (!up) {
      float* M = Mdown + c_pref[si]*32;          // [pn][32], align_corners=True
      for (int o = 0; o < pn; o++){
        double src = (pn == 1) ? 0.0 : (double)(o*(32-1)) / (double)(pn-1);
        double fl = floor(src); double tt = src - fl; int fli = (int)fl;
        for (int k = -1; k <= 2; k++){
          int j = fli + k; j = j < 0 ? 0 : (j > 31 ? 31 : j);
          float w = (float)dev_cubic((double)k - tt);
          M[o*32 + j] = M[o*32 + j] + w;
        }
      }
    } else {
      float* M = Mup + c_pref[si]*32;            // [32][pn], align_corners=False
      for (int o = 0; o < 32; o++){
        double src = ((double)o + 0.5) * (double)pn / 32.0 - 0.5;
        double fl = floor(src); double tt = src - fl; int fli = (int)fl;
        for (int k = -1; k <= 2; k++){
          int j = fli + k; j = j < 0 ? 0 : (j > pn-1 ? pn-1 : j);
          float w = (float)dev_cubic((double)k - tt);
          M[o*pn + j] = M[o*pn + j] + w;
        }
      }
    }
  }
}

// pack Phi center-column weights: wPack[pi][co*196 + ci*3 + kh] = w[pi][co][ci][kh][1]
__global__ void pack_w(const float* __restrict__ w, float* __restrict__ wPack){
  for (int e = blockIdx.x*blockDim.x + threadIdx.x; e < 4*64*196; e += gridDim.x*blockDim.x){
    int pi = e / (64*196);
    int r  = e - pi*64*196;
    int co = r / 196, m = r - co*196;
    float v = 0.0f;
    if (m < 192){
      int ci = m / 3, kh = m - ci*3;
      v = w[(((pi*64 + co)*64 + ci)*3 + kh)*3 + 1];
    }
    wPack[e] = v;
  }
}

// numpy scalar pairwise-8 sum of fl32 squares of 64 contiguous floats
__device__ float np_pairwise8_sq64(const float* a){
#pragma clang fp contract(off)
  float r0 = a[0]*a[0], r1 = a[1]*a[1], r2 = a[2]*a[2], r3 = a[3]*a[3];
  float r4 = a[4]*a[4], r5 = a[5]*a[5], r6 = a[6]*a[6], r7 = a[7]*a[7];
  for (int i = 8; i < 64; i += 8){
    float s0 = a[i+0]*a[i+0]; r0 = r0 + s0;
    float s1 = a[i+1]*a[i+1]; r1 = r1 + s1;
    float s2 = a[i+2]*a[i+2]; r2 = r2 + s2;
    float s3 = a[i+3]*a[i+3]; r3 = r3 + s3;
    float s4 = a[i+4]*a[i+4]; r4 = r4 + s4;
    float s5 = a[i+5]*a[i+5]; r5 = r5 + s5;
    float s6 = a[i+6]*a[i+6]; r6 = r6 + s6;
    float s7 = a[i+7]*a[i+7]; r7 = r7 + s7;
  }
  return ((r0 + r1) + (r2 + r3)) + ((r4 + r5) + (r6 + r7));
}

// ---- exact 3-way bf16 truncation split: a == bf(s1)+bf(s2)+bf(s3) exactly ----
__device__ inline void split3t(float a, unsigned short& s1, unsigned short& s2, unsigned short& s3){
  unsigned u1 = __float_as_uint(a);
  s1 = (unsigned short)(u1 >> 16);
  float f1 = __uint_as_float(u1 & 0xffff0000u);
  float r1 = a - f1;                                  // exact
  unsigned u2 = __float_as_uint(r1);
  s2 = (unsigned short)(u2 >> 16);
  float f2 = __uint_as_float(u2 & 0xffff0000u);
  float r2 = r1 - f2;                                 // exact, <=8 sig bits
  s3 = (unsigned short)(__float_as_uint(r2) >> 16);   // lossless
}
__device__ inline float bf_up(short h){
  return __uint_as_float(((unsigned)(unsigned short)h) << 16);
}

// ePack: per 16-code tile vt, per K-half kk, per split sp: 64 lanes x 8 bf16 (1KB chunk)
// chunk = (vt*2+kk)*3+sp ; elem-in-chunk = (g*16 + col)*8 + jj  (k = kk*32 + g*8 + jj)
__global__ void prep_emb(const float* __restrict__ emb, unsigned short* __restrict__ ePack,
                         float* __restrict__ e_sq){
#pragma clang fp contract(off)
  int v = blockIdx.x*blockDim.x + threadIdx.x;
  if (v >= VV) return;
  float row[64];
  for (int c = 0; c < CC; c++) row[c] = emb[v*CC + c];
  e_sq[v] = np_pairwise8_sq64(row);
  int vt = v >> 4, col = v & 15;
  for (int c = 0; c < CC; c++){
    unsigned short s1, s2, s3;
    split3t(row[c], s1, s2, s3);
    int kk = c >> 5, g = (c >> 3) & 3, jj = c & 7;
    size_t base = ((size_t)((vt*2 + kk)*3))*512 + (size_t)(g*16 + col)*8 + jj;
    ePack[base       ] = s1;
    ePack[base +  512] = s2;
    ePack[base + 1024] = s3;
  }
}

// init: frest=f, fhat=0, rest0 = downsample(f) at scale 0 (pn=1)
__global__ __launch_bounds__(256) void init_k(const float* __restrict__ f,
    float* frest, float* fhat, float* rest0, const float* Md0){
#pragma clang fp contract(off)
  __shared__ float frL[64][33];
  __shared__ float m0[32];
  int b = blockIdx.x, t = threadIdx.x;
  if (t < 32) m0[t] = Md0[t];
  for (int e = t; e < 2048; e += 256){
    int c = e >> 5, h = e & 31;
    float v = f[b*2048 + e];
    frL[c][h] = v;
    frest[b*2048 + e] = v;
    fhat[b*2048 + e] = 0.0f;
  }
  __syncthreads();
  if (t < 64){
    float s = 0.0f;
    for (int h = 0; h < 32; h++){ float pr = m0[h]*frL[t][h]; s = s + pr; }
    rest0[b*64 + t] = s;
  }
}

// ---------------- argmin via MFMA bf16x3 (6-product fp32 emulation) ----------------
// Round-6 numerics EXACT (sR + es, fmaf(-2,acc,t1), strict-< min, same MFMA
// order). Change: 2-round-deep register prefetch (stA/stB named sets, loop
// unrolled x2). At round r: issue loads for r+2, compute r from LDS, ds_write
// r+1's data (issued at r-1, ~2 rounds old -> landed; vmcnt wait ~free).
// Overrun reads (<=12KB past logical end) land in the widened ePack slack.

template<int PN, int NSPLIT>
__global__ __launch_bounds__(256,2) void argmin_mfma(const float* __restrict__ rest,
    const unsigned short* __restrict__ ePack, const float* __restrict__ e_sq,
    float* __restrict__ bestW, int* __restrict__ idxW)
{
#pragma clang fp contract(off)
  constexpr int VSPL = VV / NSPLIT;     // codes per block (>=128)
  constexpr int NVT  = VSPL / 16;       // 16-code tiles per block (>=8, even)
  constexpr int CH   = 2;               // tiles per staged round (12KB)
  constexpr int NR   = NVT / CH;
  static_assert(NVT % CH == 0 && NR % 2 == 0, "NR must be even");

  __shared__ __align__(16) unsigned short eS[2][CH*6*512];   // 2 x 12KB
  __shared__ float esL[VSPL];
  __shared__ float sR[RT];

  const int n0    = blockIdx.x * RT;
  const int split = blockIdx.y;
  const int v0    = split * VSPL;
  const int t     = threadIdx.x;
  const int lane  = t & 63;
  const int w     = t >> 6;
  const int m     = lane & 15;
  const int g     = lane >> 4;

  // wave w owns chunks [w*3, w*3+3) of each 12-chunk round
  const unsigned short* gW = ePack + (size_t)(v0 >> 4)*3072
                           + (size_t)w*3*512 + (size_t)lane*8;

  bf16x8 stA0, stA1, stA2, stB0, stB1, stB2;
#define LOADA(RR) do { const unsigned short* gR = gW + (size_t)(RR)*CH*6*512; \
    stA0 = *(const bf16x8*)(gR); stA1 = *(const bf16x8*)(gR + 512); \
    stA2 = *(const bf16x8*)(gR + 1024); } while(0)
#define LOADB(RR) do { const unsigned short* gR = gW + (size_t)(RR)*CH*6*512; \
    stB0 = *(const bf16x8*)(gR); stB1 = *(const bf16x8*)(gR + 512); \
    stB2 = *(const bf16x8*)(gR + 1024); } while(0)
#define WRA(BUF) do { \
    *(bf16x8*)&eS[BUF][(w*3 + 0)*512 + (size_t)lane*8] = stA0; \
    *(bf16x8*)&eS[BUF][(w*3 + 1)*512 + (size_t)lane*8] = stA1; \
    *(bf16x8*)&eS[BUF][(w*3 + 2)*512 + (size_t)lane*8] = stA2; } while(0)
#define WRB(BUF) do { \
    *(bf16x8*)&eS[BUF][(w*3 + 0)*512 + (size_t)lane*8] = stB0; \
    *(bf16x8*)&eS[BUF][(w*3 + 1)*512 + (size_t)lane*8] = stB1; \
    *(bf16x8*)&eS[BUF][(w*3 + 2)*512 + (size_t)lane*8] = stB2; } while(0)

  // earliest issue: rounds 0 and 1
  LOADA(0);
  LOADB(1);

  for (int e = t; e < VSPL; e += 256) esL[e] = e_sq[v0 + e];

  // A-fragment direct gather + in-register split (identical lane mapping and
  // identical fp32 source values to the round-3 LDS path)
  bf16x8 aF[2][2][3];                 // [rt][kk][split]
  const int rt0 = w*2;
#pragma unroll
  for (int r2 = 0; r2 < 2; r2++){
    int n = n0 + (rt0 + r2)*16 + m;
    int b = n / PN, p = n % PN;       // compile-time divisor
    const float* rb = rest + (size_t)b*CC*PN + p;
#pragma unroll
    for (int kk = 0; kk < 2; kk++){
#pragma unroll
      for (int jj = 0; jj < 8; jj++){
        int c = kk*32 + g*8 + jj;
        float a = rb[(size_t)c*PN];
        unsigned short s1, s2, s3;
        split3t(a, s1, s2, s3);
        aF[r2][kk][0][jj] = (short)s1;
        aF[r2][kk][1][jj] = (short)s2;
        aF[r2][kk][2][jj] = (short)s3;
      }
    }
  }

  // sR: exact numpy pairwise-8 row norm, straight from global (L1/L2-hot;
  // coalesced across lanes for fixed c since consecutive t -> consecutive p)
  if (t < RT){
    int n = n0 + t;
    int b = n / PN, p = n % PN;
    const float* rb = rest + (size_t)b*CC*PN + p;
    float a0 = rb[0];              float r0 = a0*a0;
    float a1 = rb[(size_t)1*PN];   float r1 = a1*a1;
    float a2 = rb[(size_t)2*PN];   float r2 = a2*a2;
    float a3 = rb[(size_t)3*PN];   float r3 = a3*a3;
    float a4 = rb[(size_t)4*PN];   float r4 = a4*a4;
    float a5 = rb[(size_t)5*PN];   float r5 = a5*a5;
    float a6 = rb[(size_t)6*PN];   float r6 = a6*a6;
    float a7 = rb[(size_t)7*PN];   float r7 = a7*a7;
    for (int i = 8; i < 64; i += 8){
      float b0 = rb[(size_t)(i+0)*PN]; float s0 = b0*b0; r0 = r0 + s0;
      float b1 = rb[(size_t)(i+1)*PN]; float s1 = b1*b1; r1 = r1 + s1;
      float b2 = rb[(size_t)(i+2)*PN]; float s2 = b2*b2; r2 = r2 + s2;
      float b3 = rb[(size_t)(i+3)*PN]; float s3 = b3*b3; r3 = r3 + s3;
      float b4 = rb[(size_t)(i+4)*PN]; float s4 = b4*b4; r4 = r4 + s4;
      float b5 = rb[(size_t)(i+5)*PN]; float s5 = b5*b5; r5 = r5 + s5;
      float b6 = rb[(size_t)(i+6)*PN]; float s6 = b6*b6; r6 = r6 + s6;
      float b7 = rb[(size_t)(i+7)*PN]; float s7 = b7*b7; r7 = r7 + s7;
    }
    sR[t] = ((r0 + r1) + (r2 + r3)) + ((r4 + r5) + (r6 + r7));
  }

  // stage round 0 (stA, issued earliest -> landed under phase-1)
  WRA(0);
  __syncthreads();

  f32x4 sRl[2];
  sRl[0] = *(const f32x4*)&sR[(rt0+0)*16 + g*4];
  sRl[1] = *(const f32x4*)&sR[(rt0+1)*16 + g*4];

  float best[2][4]; int bidx[2][4];
#pragma unroll
  for (int r2 = 0; r2 < 2; r2++)
#pragma unroll
    for (int rg = 0; rg < 4; rg++){ best[r2][rg] = 3.0e38f; bidx[r2][rg] = 0; }

  // per-acc MFMA order + epilogue identical to verified round-3 kernel
#define CTILE(eF, VT) do { \
    f32x4 acc0 = {0.f,0.f,0.f,0.f}; \
    f32x4 acc1 = {0.f,0.f,0.f,0.f}; \
    __builtin_amdgcn_s_setprio(1); \
    acc0 = __builtin_amdgcn_mfma_f32_16x16x32_bf16(aF[0][0][0], eF[0], acc0, 0,0,0); \
    acc1 = __builtin_amdgcn_mfma_f32_16x16x32_bf16(aF[1][0][0], eF[0], acc1, 0,0,0); \
    acc0 = __builtin_amdgcn_mfma_f32_16x16x32_bf16(aF[0][0][0], eF[1], acc0, 0,0,0); \
    acc1 = __builtin_amdgcn_mfma_f32_16x16x32_bf16(aF[1][0][0], eF[1], acc1, 0,0,0); \
    acc0 = __builtin_amdgcn_mfma_f32_16x16x32_bf16(aF[0][0][1], eF[0], acc0, 0,0,0); \
    acc1 = __builtin_amdgcn_mfma_f32_16x16x32_bf16(aF[1][0][1], eF[0], acc1, 0,0,0); \
    acc0 = __builtin_amdgcn_mfma_f32_16x16x32_bf16(aF[0][0][1], eF[1], acc0, 0,0,0); \
    acc1 = __builtin_amdgcn_mfma_f32_16x16x32_bf16(aF[1][0][1], eF[1], acc1, 0,0,0); \
    acc0 = __builtin_amdgcn_mfma_f32_16x16x32_bf16(aF[0][0][0], eF[2], acc0, 0,0,0); \
    acc1 = __builtin_amdgcn_mfma_f32_16x16x32_bf16(aF[1][0][0], eF[2], acc1, 0,0,0); \
    acc0 = __builtin_amdgcn_mfma_f32_16x16x32_bf16(aF[0][0][2], eF[0], acc0, 0,0,0); \
    acc1 = __builtin_amdgcn_mfma_f32_16x16x32_bf16(aF[1][0][2], eF[0], acc1, 0,0,0); \
    acc0 = __builtin_amdgcn_mfma_f32_16x16x32_bf16(aF[0][1][0], eF[3], acc0, 0,0,0); \
    acc1 = __builtin_amdgcn_mfma_f32_16x16x32_bf16(aF[1][1][0], eF[3], acc1, 0,0,0); \
    acc0 = __builtin_amdgcn_mfma_f32_16x16x32_bf16(aF[0][1][0], eF[4], acc0, 0,0,0); \
    acc1 = __builtin_amdgcn_mfma_f32_16x16x32_bf16(aF[1][1][0], eF[4], acc1, 0,0,0); \
    acc0 = __builtin_amdgcn_mfma_f32_16x16x32_bf16(aF[0][1][1], eF[3], acc0, 0,0,0); \
    acc1 = __builtin_amdgcn_mfma_f32_16x16x32_bf16(aF[1][1][1], eF[3], acc1, 0,0,0); \
    acc0 = __builtin_amdgcn_mfma_f32_16x16x32_bf16(aF[0][1][1], eF[4], acc0, 0,0,0); \
    acc1 = __builtin_amdgcn_mfma_f32_16x16x32_bf16(aF[1][1][1], eF[4], acc1, 0,0,0); \
    acc0 = __builtin_amdgcn_mfma_f32_16x16x32_bf16(aF[0][1][0], eF[5], acc0, 0,0,0); \
    acc1 = __builtin_amdgcn_mfma_f32_16x16x32_bf16(aF[1][1][0], eF[5], acc1, 0,0,0); \
    acc0 = __builtin_amdgcn_mfma_f32_16x16x32_bf16(aF[0][1][2], eF[3], acc0, 0,0,0); \
    acc1 = __builtin_amdgcn_mfma_f32_16x16x32_bf16(aF[1][1][2], eF[3], acc1, 0,0,0); \
    __builtin_amdgcn_s_setprio(0); \
    int vt_ = (VT); \
    float es = esL[vt_*16 + m]; \
    int codeBase = v0 + vt_*16 + m; \
    _Pragma("unroll") \
    for (int rg = 0; rg < 4; rg++){ \
      float t1a = sRl[0][rg] + es;                 /* fl(R + e_sq) */ \
      float da  = fmaf(-2.0f, acc0[rg], t1a);      /* == fl(t1 - 2*dot) */ \
      if (da < best[0][rg]) { best[0][rg] = da; bidx[0][rg] = codeBase; } \
      float t1b = sRl[1][rg] + es; \
      float db  = fmaf(-2.0f, acc1[rg], t1b); \
      if (db < best[1][rg]) { best[1][rg] = db; bidx[1][rg] = codeBase; } \
    } } while(0)

#define CROUND(BUF, RR) do { \
    _Pragma("unroll") \
    for (int q = 0; q < CH; q++){ \
      bf16x8 eF[6]; \
      _Pragma("unroll") \
      for (int k = 0; k < 6; k++) \
        eF[k] = *(const bf16x8*)&eS[BUF][(q*6 + k)*512 + (size_t)lane*8]; \
      CTILE(eF, (RR)*CH + q); \
    } } while(0)

  // main loop, 2 rounds per iteration (NR even). Invariants at iter top:
  // buf0 = round r data; stB = round r+1 data (issued >=1 round ago).
  for (int r = 0; r < NR; r += 2){
    LOADA(r + 2);              // issue 2 ahead (overrun lands in slack)
    CROUND(0, r);
    WRB(1);                    // round r+1 data -> buf1 (landed)
    __syncthreads();

    LOADB(r + 3);
    CROUND(1, r + 1);
    WRA(0);                    // round r+2 data -> buf0
    __syncthreads();
  }
#undef CROUND
#undef CTILE
#undef LOADA
#undef LOADB
#undef WRA
#undef WRB

  // per-row reduce over the 16 lanes sharing (lane>>4); first-min (smaller code on tie)
#pragma unroll
  for (int r2 = 0; r2 < 2; r2++)
#pragma unroll
    for (int rg = 0; rg < 4; rg++){
      float v = best[r2][rg]; int ix = bidx[r2][rg];
      for (int off = 8; off; off >>= 1){
        float ov = __shfl_down(v, off, 16);
        int   oi = __shfl_down(ix, off, 16);
        if (ov < v || (ov == v && oi < ix)) { v = ov; ix = oi; }
      }
      if ((lane & 15) == 0){
        int n = n0 + (rt0 + r2)*16 + (lane>>4)*4 + rg;
        bestW[n*NSPLIT + split] = v;
        idxW [n*NSPLIT + split] = ix;
      }
    }
}

// ---------------- fused split-reduce + upsample/gather + Phi + next-scale downsample ----------------

template<int PN, int PN2, int NSPLIT, bool LAST>
__global__ __launch_bounds__(256) void fused_phi(
    const float* __restrict__ emb,
    const float* __restrict__ bestW, const int* __restrict__ idxW,
    const float* __restrict__ Mup, const float* __restrict__ wP,
    const float* __restrict__ bias, const float* __restrict__ f,
    float* fhat, float* frest, float* levels_out, float* final_out,
    float* rest_next, const float* __restrict__ Mdown_next,
    double* partial, int si)
{
#pragma clang fp contract(off)
  __shared__ float huP[64][36];   // [ci][1+h], zero borders at 0 and 33
  __shared__ union { float hE[24*64]; float frL[64*33]; } u;   // phase-disjoint
  __shared__ float wL[64*196];    // [co][ci*3+kh], float4-clean stride
  __shared__ float mUp[32*25];    // [o][p], stride PN+1 (<=25)
  __shared__ float mDn[32*33];    // [p][h], stride 33
  __shared__ int idxL[32];
  __shared__ double red[4];
  int b = blockIdx.x, t = threadIdx.x;

  // fold of argmin_reduce: cross-split first-min (splits ascending, strict <)
  if (t < PN){
    int base = (b*PN + t)*NSPLIT;
    float v = bestW[base]; int ix = idxW[base];
#pragma unroll
    for (int s = 1; s < NSPLIT; s++){
      float ov = bestW[base + s];
      if (ov < v) { v = ov; ix = idxW[base + s]; }
    }
    idxL[t] = ix;
  }
  if (t < 64){ huP[t][0] = 0.0f; huP[t][33] = 0.0f; huP[t][34] = 0.0f; huP[t][35] = 0.0f; }
  // coalesced float4 staging of packed weights (12544 floats = 3136 float4)
  for (int e = t; e < 3136; e += 256)
    *(float4*)&wL[e*4] = *(const float4*)&wP[e*4];
  if (PN2 > 0){
    for (int e = t; e < PN2*32; e += 256){
      int p = e >> 5, h = e & 31;
      mDn[p*33 + h] = Mdown_next[e];
    }
  }
  if (!LAST){
    for (int e = t; e < 32*PN; e += 256){
      int o = e / PN, p = e - o*PN;
      mUp[o*(PN+1) + p] = Mup[e];
    }
  }
  __syncthreads();

  if (!LAST){
    for (int e = t; e < PN*64; e += 256){
      int p = e >> 6, c = e & 63;
      u.hE[p*64 + c] = emb[idxL[p]*64 + c];
    }
    __syncthreads();
    for (int e = t; e < 2048; e += 256){
      int c = e >> 5, o = e & 31;
      const float* mr = &mUp[o*(PN+1)];
      float s = 0.0f;
#pragma unroll
      for (int p = 0; p < PN; p++){ float pr = mr[p]*u.hE[p*64 + c]; s = s + pr; }
      huP[c][1 + o] = s;
    }
  } else {
    for (int e = t; e < 2048; e += 256){
      int h = e >> 6, c = e & 63;
      huP[c][1 + h] = emb[idxL[h]*64 + c];
    }
  }
  __syncthreads();   // hE dead after this point

  // conv3 along H; vectorized LDS reads (aligned: huP row base 144B, h0 multiple of 8)
  int co = t >> 2, h0 = (t & 3) * 8;
  float y[8];
#pragma unroll
  for (int uu = 0; uu < 8; uu++) y[uu] = 0.0f;
  for (int ci4 = 0; ci4 < 64; ci4 += 4){
    float4 wa = *(const float4*)&wL[co*196 + ci4*3];
    float4 wb = *(const float4*)&wL[co*196 + ci4*3 + 4];
    float4 wc = *(const float4*)&wL[co*196 + ci4*3 + 8];
    float wv[12] = {wa.x,wa.y,wa.z,wa.w, wb.x,wb.y,wb.z,wb.w, wc.x,wc.y,wc.z,wc.w};
#pragma unroll
    for (int q = 0; q < 4; q++){
      int ci = ci4 + q;
      float4 xa = *(const float4*)&huP[ci][h0];
      float4 xb = *(const float4*)&huP[ci][h0 + 4];
      float2 xc = *(const float2*)&huP[ci][h0 + 8];
      float x[10] = {xa.x,xa.y,xa.z,xa.w, xb.x,xb.y,xb.z,xb.w, xc.x,xc.y};
      float w0 = wv[q*3], w1 = wv[q*3+1], w2 = wv[q*3+2];
#pragma unroll
      for (int uu = 0; uu < 8; uu++){
        y[uu] = fmaf(w0, x[uu],   y[uu]);
        y[uu] = fmaf(w1, x[uu+1], y[uu]);
        y[uu] = fmaf(w2, x[uu+2], y[uu]);
      }
    }
  }

  float bb = bias[co];
  double lsum = 0.0;
  int base = b*2048 + co*32 + h0;
#pragma unroll
  for (int uu = 0; uu < 8; uu++){
    float yv = y[uu] + bb;                           // conv + bias (after)
    float hp = 0.5f*huP[co][1 + h0 + uu] + 0.5f*yv;  // h*(1-r) + y*r, r=0.5
    float fh = fhat[base+uu] + hp;
    fhat[base+uu] = fh;
    float fr = frest[base+uu] - hp;
    frest[base+uu] = fr;
    u.frL[co*33 + h0 + uu] = fr;
    float fv = f[base+uu];
    float dv = fh - fv;
    lsum += (double)dv*(double)dv;
    levels_out[base+uu] = fh;
    if (LAST) final_out[base+uu] = dv + fv;    // straight-through: fl(fl(fh-f)+f)
  }
  for (int off = 32; off; off >>= 1) lsum += __shfl_down(lsum, off);
  if ((t & 63) == 0) red[t >> 6] = lsum;
  __syncthreads();

  if (PN2 > 0){
    for (int e = t; e < 64*PN2; e += 256){
      int c = e / PN2, p = e - c*PN2;
      const float* mr = &mDn[p*33];
      float s = 0.0f;
#pragma unroll
      for (int h = 0; h < 32; h++){ float pr = mr[h]*u.frL[c*33 + h]; s = s + pr; }
      rest_next[(b*64 + c)*PN2 + p] = s;
    }
  }
  if (t == 0) atomicAdd(&partial[si], red[0] + red[1] + red[2] + red[3]);
}

__global__ void finalize(const double* partial, float* out_loss){
#pragma clang fp contract(off)
  float L = 0.0f;
  for (int si = 0; si < 10; si++){
    float m = (float)(partial[si] / (double)NEL);
    float t1 = 0.25f * m;
    L = L + t1;
    L = L + m;
  }
  L = L / 10.0f;
  *out_loss = L;
}

// ---------------- host ----------------

struct Ptrs {
  const float *f, *emb;
  unsigned short *ePack;
  float *e_sq, *frest, *fhat, *rest, *Mdown, *Mup, *wPack, *bestW;
  int *idxW;
  double *partial;
  float *out0, *out_levels;
  const float *phi_b;
};

template<int PN, int PN2, int NSPLIT, bool LAST>
static void run_scale(const Ptrs& P, int si, int pi, int mup_off, int mdn_off,
                      hipStream_t stream){
  constexpr int N = BB*PN;
  dim3 ag(N/RT, NSPLIT);
  const float* restp = LAST ? P.f : P.rest;
  argmin_mfma<PN, NSPLIT><<<ag, 256, 0, stream>>>(restp, P.ePack, P.e_sq, P.bestW, P.idxW);
  fused_phi<PN, PN2, NSPLIT, LAST><<<BB, 256, 0, stream>>>(
      P.emb, P.bestW, P.idxW, P.Mup + mup_off,
      P.wPack + (size_t)pi*64*196, P.phi_b + (size_t)pi*CC,
      P.f, P.fhat, P.frest, P.out_levels + (size_t)si*NEL, P.out0,
      P.rest, P.Mdown + mdn_off, P.partial, si);
}

extern "C" void kernel_launch(void* const* d_in, const int* in_sizes, int n_in,
                              void* d_out, int out_size, void* d_ws, size_t ws_size,
                              hipStream_t stream) {
  const float* f     = (const float*)d_in[0];
  const float* emb   = (const float*)d_in[1];
  const float* phi_w = (const float*)d_in[2];
  const float* phi_b = (const float*)d_in[3];
  float* out0       = (float*)d_out;
  float* out_loss   = out0 + NEL;
  float* out_levels = out0 + NEL + 1;

  double* partial      = (double*)d_ws;                 // 16
  unsigned short* ePack = (unsigned short*)(partial + 16); // 786432 u16 + 16384 slack (1.57MB)
  float*  e_sq    = (float*)(ePack + 786432 + 16384);   // 4096
  float*  frest   = e_sq + 4096;                        // NEL
  float*  fhat    = frest + NEL;                        // NEL
  float*  rest    = fhat + NEL;                         // NEL (max)
  float*  Mdown   = rest + NEL;                         // 3584
  float*  Mup     = Mdown + 3584;                       // 3584
  float*  wPack   = Mup + 3584;                         // 50176
  float*  bestW   = wPack + 50176;                      // 262144
  int*    idxW    = (int*)(bestW + 262144);             // 262144

  // pi table: exact IEEE-fp64 mirror of np.linspace + argmin(|TICKS - si/9|)
  double q = 1.0/3.0; q = q/4.0;
  double start = q;
  double stop  = 1.0 - q;
  double delta = stop - start;
  double step  = delta/3.0;
  double ticks[4];
  ticks[0] = start;
  ticks[1] = step + start;
  { double t2 = 2.0*step; ticks[2] = t2 + start; }
  ticks[3] = stop;
  int pi_tab[10];
  for (int si = 0; si < 10; si++){
    double x = (double)si / 9.0;
    int bi = 0; double bd = fabs(ticks[0] - x);
    for (int i2 = 1; i2 < 4; i2++){
      double dd = fabs(ticks[i2] - x);
      if (dd < bd) { bd = dd; bi = i2; }
    }
    pi_tab[si] = bi;
  }

  static const int pref[10] = {0,1,3,6,10,16,25,38,56,80};

  gen_setup<<<1, 64, 0, stream>>>(Mdown, Mup, partial);
  pack_w<<<64, 256, 0, stream>>>(phi_w, wPack);
  prep_emb<<<16, 256, 0, stream>>>(emb, ePack, e_sq);
  init_k<<<BB, 256, 0, stream>>>(f, frest, fhat, rest, Mdown /* scale0: [1][32] */);

  Ptrs P = {f, emb, ePack, e_sq, frest, fhat, rest, Mdown, Mup, wPack, bestW,
            idxW, partial, out0, out_levels, phi_b};

  // scale 9 quantizes f itself (reference: rest = f), so si=8 needs no downsample (PN2=0)
  run_scale< 1,  2, 32, false>(P, 0, pi_tab[0], pref[0]*32, pref[1]*32, stream);
  run_scale< 2,  3, 32, false>(P, 1, pi_tab[1], pref[1]*32, pref[2]*32, stream);
  run_scale< 3,  4, 32, false>(P, 2, pi_tab[2], pref[2]*32, pref[3]*32, stream);
  run_scale< 4,  6, 32, false>(P, 3, pi_tab[3], pref[3]*32, pref[4]*32, stream);
  run_scale< 6,  9, 16, false>(P, 4, pi_tab[4], pref[4]*32, pref[5]*32, stream);
  run_scale< 9, 13, 16, false>(P, 5, pi_tab[5], pref[5]*32, pref[6]*32, stream);
  run_scale<13, 18,  8, false>(P, 6, pi_tab[6], pref[6]*32, pref[7]*32, stream);
  run_scale<18, 24,  8, false>(P, 7, pi_tab[7], pref[7]*32, pref[8]*32, stream);
  run_scale<24,  0,  8, false>(P, 8, pi_tab[8], pref[8]*32, 0,          stream);
  run_scale<32,  0,  8, true >(P, 9, pi_tab[9], pref[9]*32, 0,          stream);

  finalize<<<1, 1, 0, stream>>>(partial, out_loss);
}

// Round 8
// 1012.476 us; speedup vs baseline: 1.0160x; 1.0160x over previous
//
#include <hip/hip_runtime.h>
#include <math.h>

#define BB 1024
#define CC 64
#define HH 32
#define VV 4096
#define NEL (BB*CC*HH)   // 2097152

#define RT 128        // rows per argmin block

typedef __attribute__((ext_vector_type(4))) float f32x4;
typedef __attribute__((ext_vector_type(8))) short bf16x8;   // 8 bf16 = 4 VGPRs

// ---------------- setup ----------------

__device__ double dev_cubic(double x){
#pragma clang fp contract(off)
  const double A = -0.75;
  x = fabs(x);
  if (x <= 1.0) return ((A + 2.0)*x - (A + 3.0))*x*x + 1.0;
  if (x < 2.0)  return A*(((x - 5.0)*x + 8.0)*x - 4.0);
  return 0.0;
}

__device__ __constant__ int c_vpatch[10] = {1,2,3,4,6,9,13,18,24,32};
__device__ __constant__ int c_pref[10]   = {0,1,3,6,10,16,25,38,56,80};

// numpy scalar pairwise-8 sum of fl32 squares of 64 contiguous floats
__device__ float np_pairwise8_sq64(const float* a){
#pragma clang fp contract(off)
  float r0 = a[0]*a[0], r1 = a[1]*a[1], r2 = a[2]*a[2], r3 = a[3]*a[3];
  float r4 = a[4]*a[4], r5 = a[5]*a[5], r6 = a[6]*a[6], r7 = a[7]*a[7];
  for (int i = 8; i < 64; i += 8){
    float s0 = a[i+0]*a[i+0]; r0 = r0 + s0;
    float s1 = a[i+1]*a[i+1]; r1 = r1 + s1;
    float s2 = a[i+2]*a[i+2]; r2 = r2 + s2;
    float s3 = a[i+3]*a[i+3]; r3 = r3 + s3;
    float s4 = a[i+4]*a[i+4]; r4 = r4 + s4;
    float s5 = a[i+5]*a[i+5]; r5 = r5 + s5;
    float s6 = a[i+6]*a[i+6]; r6 = r6 + s6;
    float s7 = a[i+7]*a[i+7]; r7 = r7 + s7;
  }
  return ((r0 + r1) + (r2 + r3)) + ((r4 + r5) + (r6 + r7));
}

// ---- exact 3-way bf16 truncation split: a == bf(s1)+bf(s2)+bf(s3) exactly ----
__device__ inline void split3t(float a, unsigned short& s1, unsigned short& s2, unsigned short& s3){
  unsigned u1 = __float_as_uint(a);
  s1 = (unsigned short)(u1 >> 16);
  float f1 = __uint_as_float(u1 & 0xffff0000u);
  float r1 = a - f1;                                  // exact
  unsigned u2 = __float_as_uint(r1);
  s2 = (unsigned short)(u2 >> 16);
  float f2 = __uint_as_float(u2 & 0xffff0000u);
  float r2 = r1 - f2;                                 // exact, <=8 sig bits
  s3 = (unsigned short)(__float_as_uint(r2) >> 16);   // lossless
}

// ---------------- fused setup: init + pack_w + prep_emb + gen_setup ----------
// Roles by blockIdx (no cross-role dependencies):
//  [0,1024)    init: frest=f, fhat=0, rest0[b][c] = f[b][c][0]
//              (exact: 32->1 bicubic align_corners=True matrix is e_0 —
//               cubic(-1)=cubic(1)=cubic(2)=0.0, cubic(0)=1.0 in fp32, and
//               the reference's +0.0 terms preserve the value bit-exactly)
//  [1024,1088) pack_w (64 blocks x 784 elems)
//  [1088,1152) prep_emb, coalesced via LDS transpose (64 v per block)
//  1152        gen_setup (Mdown/Mup tables + partial zeroing)
__global__ __launch_bounds__(256) void setup_all(
    const float* __restrict__ f, const float* __restrict__ emb,
    const float* __restrict__ phi_w,
    float* frest, float* fhat, float* rest0,
    float* Mdown, float* Mup, double* partial,
    float* wPack, unsigned short* ePack, float* e_sq)
{
#pragma clang fp contract(off)
  __shared__ float rows[64][65];     // prep role only (16.6KB)
  int blk = blockIdx.x, t = threadIdx.x;

  if (blk < 1024){
    int b = blk;
    for (int e = t; e < 2048; e += 256){
      float v = f[b*2048 + e];
      frest[b*2048 + e] = v;
      fhat[b*2048 + e] = 0.0f;
    }
    if (t < 64) rest0[b*64 + t] = f[b*2048 + t*32];   // h=0 sample, exact
  } else if (blk < 1088){
    int e0 = (blk - 1024)*784;       // 4*64*196 = 50176 = 64*784
    for (int i = t; i < 784; i += 256){
      int e = e0 + i;
      int pi = e / (64*196);
      int r  = e - pi*64*196;
      int co = r / 196, m = r - co*196;
      float v = 0.0f;
      if (m < 192){
        int ci = m / 3, kh = m - ci*3;
        v = phi_w[(((pi*64 + co)*64 + ci)*3 + kh)*3 + 1];
      }
      wPack[e] = v;
    }
  } else if (blk < 1152){
    int v0 = (blk - 1088)*64;
    for (int e = t; e < 4096; e += 256){
      int vl = e >> 6, c = e & 63;
      rows[vl][c] = emb[(size_t)(v0 + vl)*64 + c];   // coalesced
    }
    __syncthreads();
    if (t < 64){
      int v = v0 + t;
      e_sq[v] = np_pairwise8_sq64(&rows[t][0]);      // exact numpy order
      int vt = v >> 4, col = v & 15;
#pragma unroll
      for (int o = 0; o < 8; o++){
        bf16x8 v1, v2, v3;
#pragma unroll
        for (int jj = 0; jj < 8; jj++){
          unsigned short s1, s2, s3;
          split3t(rows[t][o*8 + jj], s1, s2, s3);
          v1[jj] = (short)s1; v2[jj] = (short)s2; v3[jj] = (short)s3;
        }
        int kk = o >> 2, g = o & 3;
        size_t base = ((size_t)((vt*2 + kk)*3))*512 + (size_t)(g*16 + col)*8;
        *(bf16x8*)&ePack[base       ] = v1;
        *(bf16x8*)&ePack[base +  512] = v2;
        *(bf16x8*)&ePack[base + 1024] = v3;
      }
    }
  } else {
    for (int i = t; i < 3584; i += 256) { Mdown[i] = 0.0f; Mup[i] = 0.0f; }
    if (t < 16) partial[t] = 0.0;
    __syncthreads();
    if (t < 20) {
      int si = t >> 1; int up = t & 1;
      int pn = c_vpatch[si];
      if (!up) {
        float* M = Mdown + c_pref[si]*32;          // [pn][32], align_corners=True
        for (int o = 0; o < pn; o++){
          double src = (pn == 1) ? 0.0 : (double)(o*(32-1)) / (double)(pn-1);
          double fl = floor(src); double tt = src - fl; int fli = (int)fl;
          for (int k = -1; k <= 2; k++){
            int j = fli + k; j = j < 0 ? 0 : (j > 31 ? 31 : j);
            float w = (float)dev_cubic((double)k - tt);
            M[o*32 + j] = M[o*32 + j] + w;
          }
        }
      } else {
        float* M = Mup + c_pref[si]*32;            // [32][pn], align_corners=False
        for (int o = 0; o < 32; o++){
          double src = ((double)o + 0.5) * (double)pn / 32.0 - 0.5;
          double fl = floor(src); double tt = src - fl; int fli = (int)fl;
          for (int k = -1; k <= 2; k++){
            int j = fli + k; j = j < 0 ? 0 : (j > pn-1 ? pn-1 : j);
            float w = (float)dev_cubic((double)k - tt);
            M[o*pn + j] = M[o*pn + j] + w;
          }
        }
      }
    }
  }
}

// ---------------- argmin via MFMA bf16x3 (6-product fp32 emulation) ----------------
// Round-6 form VERBATIM (measured 91.2us, VGPR 72, no spill). Numerics: sR + es,
// fmaf(-2,acc,t1), strict-< min, fixed MFMA order. 1-round register prefetch,
// CH=2 LDS dbuf, launch_bounds(256,2) (cap 128 regs; actual ~72 -> ~6 blocks/CU).

template<int PN, int NSPLIT>
__global__ __launch_bounds__(256,2) void argmin_mfma(const float* __restrict__ rest,
    const unsigned short* __restrict__ ePack, const float* __restrict__ e_sq,
    float* __restrict__ bestW, int* __restrict__ idxW)
{
#pragma clang fp contract(off)
  constexpr int VSPL = VV / NSPLIT;     // codes per block (>=128)
  constexpr int NVT  = VSPL / 16;       // 16-code tiles per block (>=8, even)
  constexpr int CH   = 2;               // tiles per staged round (12KB)
  constexpr int NR   = NVT / CH;
  static_assert(NVT % CH == 0, "NVT must be multiple of CH");

  __shared__ __align__(16) unsigned short eS[2][CH*6*512];   // 2 x 12KB
  __shared__ float esL[VSPL];
  __shared__ float sR[RT];

  const int n0    = blockIdx.x * RT;
  const int split = blockIdx.y;
  const int v0    = split * VSPL;
  const int t     = threadIdx.x;
  const int lane  = t & 63;
  const int w     = t >> 6;
  const int m     = lane & 15;
  const int g     = lane >> 4;

  // wave w owns chunks [w*3, w*3+3) of each 12-chunk round
  const unsigned short* gW = ePack + (size_t)(v0 >> 4)*3072
                           + (size_t)w*3*512 + (size_t)lane*8;
  bf16x8 st[3];
#pragma unroll
  for (int c = 0; c < 3; c++) st[c] = *(const bf16x8*)(gW + c*512);

  for (int e = t; e < VSPL; e += 256) esL[e] = e_sq[v0 + e];

  // A-fragment direct gather + in-register split
  bf16x8 aF[2][2][3];                 // [rt][kk][split]
  const int rt0 = w*2;
#pragma unroll
  for (int r2 = 0; r2 < 2; r2++){
    int n = n0 + (rt0 + r2)*16 + m;
    int b = n / PN, p = n % PN;       // compile-time divisor
    const float* rb = rest + (size_t)b*CC*PN + p;
#pragma unroll
    for (int kk = 0; kk < 2; kk++){
#pragma unroll
      for (int jj = 0; jj < 8; jj++){
        int c = kk*32 + g*8 + jj;
        float a = rb[(size_t)c*PN];
        unsigned short s1, s2, s3;
        split3t(a, s1, s2, s3);
        aF[r2][kk][0][jj] = (short)s1;
        aF[r2][kk][1][jj] = (short)s2;
        aF[r2][kk][2][jj] = (short)s3;
      }
    }
  }

  // sR: exact numpy pairwise-8 row norm, straight from global
  if (t < RT){
    int n = n0 + t;
    int b = n / PN, p = n % PN;
    const float* rb = rest + (size_t)b*CC*PN + p;
    float a0 = rb[0];              float r0 = a0*a0;
    float a1 = rb[(size_t)1*PN];   float r1 = a1*a1;
    float a2 = rb[(size_t)2*PN];   float r2 = a2*a2;
    float a3 = rb[(size_t)3*PN];   float r3 = a3*a3;
    float a4 = rb[(size_t)4*PN];   float r4 = a4*a4;
    float a5 = rb[(size_t)5*PN];   float r5 = a5*a5;
    float a6 = rb[(size_t)6*PN];   float r6 = a6*a6;
    float a7 = rb[(size_t)7*PN];   float r7 = a7*a7;
    for (int i = 8; i < 64; i += 8){
      float b0 = rb[(size_t)(i+0)*PN]; float s0 = b0*b0; r0 = r0 + s0;
      float b1 = rb[(size_t)(i+1)*PN]; float s1 = b1*b1; r1 = r1 + s1;
      float b2 = rb[(size_t)(i+2)*PN]; float s2 = b2*b2; r2 = r2 + s2;
      float b3 = rb[(size_t)(i+3)*PN]; float s3 = b3*b3; r3 = r3 + s3;
      float b4 = rb[(size_t)(i+4)*PN]; float s4 = b4*b4; r4 = r4 + s4;
      float b5 = rb[(size_t)(i+5)*PN]; float s5 = b5*b5; r5 = r5 + s5;
      float b6 = rb[(size_t)(i+6)*PN]; float s6 = b6*b6; r6 = r6 + s6;
      float b7 = rb[(size_t)(i+7)*PN]; float s7 = b7*b7; r7 = r7 + s7;
    }
    sR[t] = ((r0 + r1) + (r2 + r3)) + ((r4 + r5) + (r6 + r7));
  }

  // stage round 0
#pragma unroll
  for (int c = 0; c < 3; c++)
    *(bf16x8*)&eS[0][(w*3 + c)*512 + (size_t)lane*8] = st[c];
  __syncthreads();

  f32x4 sRl[2];
  sRl[0] = *(const f32x4*)&sR[(rt0+0)*16 + g*4];
  sRl[1] = *(const f32x4*)&sR[(rt0+1)*16 + g*4];

  float best[2][4]; int bidx[2][4];
#pragma unroll
  for (int r2 = 0; r2 < 2; r2++)
#pragma unroll
    for (int rg = 0; rg < 4; rg++){ best[r2][rg] = 3.0e38f; bidx[r2][rg] = 0; }

  // per-acc MFMA order + epilogue identical to verified round-3 kernel
#define CTILE(eF, VT) do { \
    f32x4 acc0 = {0.f,0.f,0.f,0.f}; \
    f32x4 acc1 = {0.f,0.f,0.f,0.f}; \
    __builtin_amdgcn_s_setprio(1); \
    acc0 = __builtin_amdgcn_mfma_f32_16x16x32_bf16(aF[0][0][0], eF[0], acc0, 0,0,0); \
    acc1 = __builtin_amdgcn_mfma_f32_16x16x32_bf16(aF[1][0][0], eF[0], acc1, 0,0,0); \
    acc0 = __builtin_amdgcn_mfma_f32_16x16x32_bf16(aF[0][0][0], eF[1], acc0, 0,0,0); \
    acc1 = __builtin_amdgcn_mfma_f32_16x16x32_bf16(aF[1][0][0], eF[1], acc1, 0,0,0); \
    acc0 = __builtin_amdgcn_mfma_f32_16x16x32_bf16(aF[0][0][1], eF[0], acc0, 0,0,0); \
    acc1 = __builtin_amdgcn_mfma_f32_16x16x32_bf16(aF[1][0][1], eF[0], acc1, 0,0,0); \
    acc0 = __builtin_amdgcn_mfma_f32_16x16x32_bf16(aF[0][0][1], eF[1], acc0, 0,0,0); \
    acc1 = __builtin_amdgcn_mfma_f32_16x16x32_bf16(aF[1][0][1], eF[1], acc1, 0,0,0); \
    acc0 = __builtin_amdgcn_mfma_f32_16x16x32_bf16(aF[0][0][0], eF[2], acc0, 0,0,0); \
    acc1 = __builtin_amdgcn_mfma_f32_16x16x32_bf16(aF[1][0][0], eF[2], acc1, 0,0,0); \
    acc0 = __builtin_amdgcn_mfma_f32_16x16x32_bf16(aF[0][0][2], eF[0], acc0, 0,0,0); \
    acc1 = __builtin_amdgcn_mfma_f32_16x16x32_bf16(aF[1][0][2], eF[0], acc1, 0,0,0); \
    acc0 = __builtin_amdgcn_mfma_f32_16x16x32_bf16(aF[0][1][0], eF[3], acc0, 0,0,0); \
    acc1 = __builtin_amdgcn_mfma_f32_16x16x32_bf16(aF[1][1][0], eF[3], acc1, 0,0,0); \
    acc0 = __builtin_amdgcn_mfma_f32_16x16x32_bf16(aF[0][1][0], eF[4], acc0, 0,0,0); \
    acc1 = __builtin_amdgcn_mfma_f32_16x16x32_bf16(aF[1][1][0], eF[4], acc1, 0,0,0); \
    acc0 = __builtin_amdgcn_mfma_f32_16x16x32_bf16(aF[0][1][1], eF[3], acc0, 0,0,0); \
    acc1 = __builtin_amdgcn_mfma_f32_16x16x32_bf16(aF[1][1][1], eF[3], acc1, 0,0,0); \
    acc0 = __builtin_amdgcn_mfma_f32_16x16x32_bf16(aF[0][1][1], eF[4], acc0, 0,0,0); \
    acc1 = __builtin_amdgcn_mfma_f32_16x16x32_bf16(aF[1][1][1], eF[4], acc1, 0,0,0); \
    acc0 = __builtin_amdgcn_mfma_f32_16x16x32_bf16(aF[0][1][0], eF[5], acc0, 0,0,0); \
    acc1 = __builtin_amdgcn_mfma_f32_16x16x32_bf16(aF[1][1][0], eF[5], acc1, 0,0,0); \
    acc0 = __builtin_amdgcn_mfma_f32_16x16x32_bf16(aF[0][1][2], eF[3], acc0, 0,0,0); \
    acc1 = __builtin_amdgcn_mfma_f32_16x16x32_bf16(aF[1][1][2], eF[3], acc1, 0,0,0); \
    __builtin_amdgcn_s_setprio(0); \
    int vt_ = (VT); \
    float es = esL[vt_*16 + m]; \
    int codeBase = v0 + vt_*16 + m; \
    _Pragma("unroll") \
    for (int rg = 0; rg < 4; rg++){ \
      float t1a = sRl[0][rg] + es;                 /* fl(R + e_sq) */ \
      float da  = fmaf(-2.0f, acc0[rg], t1a);      /* == fl(t1 - 2*dot) */ \
      if (da < best[0][rg]) { best[0][rg] = da; bidx[0][rg] = codeBase; } \
      float t1b = sRl[1][rg] + es; \
      float db  = fmaf(-2.0f, acc1[rg], t1b); \
      if (db < best[1][rg]) { best[1][rg] = db; bidx[1][rg] = codeBase; } \
    } } while(0)

  int cur = 0;
  for (int r = 0; r < NR; r++){
    if (r + 1 < NR){
      const unsigned short* gR = gW + (size_t)(r+1)*CH*6*512;
#pragma unroll
      for (int c = 0; c < 3; c++) st[c] = *(const bf16x8*)(gR + c*512);
    }
#pragma unroll
    for (int q = 0; q < CH; q++){
      bf16x8 eF[6];
#pragma unroll
      for (int k = 0; k < 6; k++)
        eF[k] = *(const bf16x8*)&eS[cur][(q*6 + k)*512 + (size_t)lane*8];
      CTILE(eF, r*CH + q);
    }
    if (r + 1 < NR){
#pragma unroll
      for (int c = 0; c < 3; c++)
        *(bf16x8*)&eS[cur ^ 1][(w*3 + c)*512 + (size_t)lane*8] = st[c];
    }
    __syncthreads();
    cur ^= 1;
  }
#undef CTILE

  // per-row reduce over the 16 lanes sharing (lane>>4); first-min (smaller code on tie)
#pragma unroll
  for (int r2 = 0; r2 < 2; r2++)
#pragma unroll
    for (int rg = 0; rg < 4; rg++){
      float v = best[r2][rg]; int ix = bidx[r2][rg];
      for (int off = 8; off; off >>= 1){
        float ov = __shfl_down(v, off, 16);
        int   oi = __shfl_down(ix, off, 16);
        if (ov < v || (ov == v && oi < ix)) { v = ov; ix = oi; }
      }
      if ((lane & 15) == 0){
        int n = n0 + (rt0 + r2)*16 + (lane>>4)*4 + rg;
        bestW[n*NSPLIT + split] = v;
        idxW [n*NSPLIT + split] = ix;
      }
    }
}

// ---------------- fused split-reduce + upsample/gather + Phi + next-scale downsample ----------------
// Change vs round 6: wL LDS staging REMOVED (weights read directly from wP;
// same values, same fmaf order -> bit-identical). LDS ~75.6KB -> ~25.4KB,
// occupancy 2 -> ~6 blocks/CU.

template<int PN, int PN2, int NSPLIT, bool LAST>
__global__ __launch_bounds__(256) void fused_phi(
    const float* __restrict__ emb,
    const float* __restrict__ bestW, const int* __restrict__ idxW,
    const float* __restrict__ Mup, const float* __restrict__ wP,
    const float* __restrict__ bias, const float* __restrict__ f,
    float* fhat, float* frest, float* levels_out, float* final_out,
    float* rest_next, const float* __restrict__ Mdown_next,
    double* partial, int si)
{
#pragma clang fp contract(off)
  __shared__ float huP[64][36];   // [ci][1+h], zero borders at 0 and 33
  __shared__ union { float hE[24*64]; float frL[64*33]; } u;   // phase-disjoint
  __shared__ float mUp[32*25];    // [o][p], stride PN+1 (<=25)
  __shared__ float mDn[32*33];    // [p][h], stride 33
  __shared__ int idxL[32];
  __shared__ double red[4];
  int b = blockIdx.x, t = threadIdx.x;

  // fold of argmin_reduce: cross-split first-min (splits ascending, strict <)
  if (t < PN){
    int base = (b*PN + t)*NSPLIT;
    float v = bestW[base]; int ix = idxW[base];
#pragma unroll
    for (int s = 1; s < NSPLIT; s++){
      float ov = bestW[base + s];
      if (ov < v) { v = ov; ix = idxW[base + s]; }
    }
    idxL[t] = ix;
  }
  if (t < 64){ huP[t][0] = 0.0f; huP[t][33] = 0.0f; huP[t][34] = 0.0f; huP[t][35] = 0.0f; }
  if (PN2 > 0){
    for (int e = t; e < PN2*32; e += 256){
      int p = e >> 5, h = e & 31;
      mDn[p*33 + h] = Mdown_next[e];
    }
  }
  if (!LAST){
    for (int e = t; e < 32*PN; e += 256){
      int o = e / PN, p = e - o*PN;
      mUp[o*(PN+1) + p] = Mup[e];
    }
  }
  __syncthreads();

  if (!LAST){
    for (int e = t; e < PN*64; e += 256){
      int p = e >> 6, c = e & 63;
      u.hE[p*64 + c] = emb[idxL[p]*64 + c];
    }
    __syncthreads();
    for (int e = t; e < 2048; e += 256){
      int c = e >> 5, o = e & 31;
      const float* mr = &mUp[o*(PN+1)];
      float s = 0.0f;
#pragma unroll
      for (int p = 0; p < PN; p++){ float pr = mr[p]*u.hE[p*64 + c]; s = s + pr; }
      huP[c][1 + o] = s;
    }
  } else {
    for (int e = t; e < 2048; e += 256){
      int h = e >> 6, c = e & 63;
      huP[c][1 + h] = emb[idxL[h]*64 + c];
    }
  }
  __syncthreads();   // hE dead after this point

  // conv3 along H; weights direct from global (L2-hot, broadcast across the
  // 4 threads sharing co); huP via vectorized LDS reads
  int co = t >> 2, h0 = (t & 3) * 8;
  float y[8];
#pragma unroll
  for (int uu = 0; uu < 8; uu++) y[uu] = 0.0f;
  for (int ci4 = 0; ci4 < 64; ci4 += 4){
    float4 wa = *(const float4*)&wP[co*196 + ci4*3];
    float4 wb = *(const float4*)&wP[co*196 + ci4*3 + 4];
    float4 wc = *(const float4*)&wP[co*196 + ci4*3 + 8];
    float wv[12] = {wa.x,wa.y,wa.z,wa.w, wb.x,wb.y,wb.z,wb.w, wc.x,wc.y,wc.z,wc.w};
#pragma unroll
    for (int q = 0; q < 4; q++){
      int ci = ci4 + q;
      float4 xa = *(const float4*)&huP[ci][h0];
      float4 xb = *(const float4*)&huP[ci][h0 + 4];
      float2 xc = *(const float2*)&huP[ci][h0 + 8];
      float x[10] = {xa.x,xa.y,xa.z,xa.w, xb.x,xb.y,xb.z,xb.w, xc.x,xc.y};
      float w0 = wv[q*3], w1 = wv[q*3+1], w2 = wv[q*3+2];
#pragma unroll
      for (int uu = 0; uu < 8; uu++){
        y[uu] = fmaf(w0, x[uu],   y[uu]);
        y[uu] = fmaf(w1, x[uu+1], y[uu]);
        y[uu] = fmaf(w2, x[uu+2], y[uu]);
      }
    }
  }

  float bb = bias[co];
  double lsum = 0.0;
  int base = b*2048 + co*32 + h0;
#pragma unroll
  for (int uu = 0; uu < 8; uu++){
    float yv = y[uu] + bb;                           // conv + bias (after)
    float hp = 0.5f*huP[co][1 + h0 + uu] + 0.5f*yv;  // h*(1-r) + y*r, r=0.5
    float fh = fhat[base+uu] + hp;
    fhat[base+uu] = fh;
    float fr = frest[base+uu] - hp;
    frest[base+uu] = fr;
    u.frL[co*33 + h0 + uu] = fr;
    float fv = f[base+uu];
    float dv = fh - fv;
    lsum += (double)dv*(double)dv;
    levels_out[base+uu] = fh;
    if (LAST) final_out[base+uu] = dv + fv;    // straight-through: fl(fl(fh-f)+f)
  }
  for (int off = 32; off; off >>= 1) lsum += __shfl_down(lsum, off);
  if ((t & 63) == 0) red[t >> 6] = lsum;
  __syncthreads();

  if (PN2 > 0){
    for (int e = t; e < 64*PN2; e += 256){
      int c = e / PN2, p = e - c*PN2;
      const float* mr = &mDn[p*33];
      float s = 0.0f;
#pragma unroll
      for (int h = 0; h < 32; h++){ float pr = mr[h]*u.frL[c*33 + h]; s = s + pr; }
      rest_next[(b*64 + c)*PN2 + p] = s;
    }
  }
  if (t == 0) atomicAdd(&partial[si], red[0] + red[1] + red[2] + red[3]);
}

__global__ void finalize(const double* partial, float* out_loss){
#pragma clang fp contract(off)
  float L = 0.0f;
  for (int si = 0; si < 10; si++){
    float m = (float)(partial[si] / (double)NEL);
    float t1 = 0.25f * m;
    L = L + t1;
    L = L + m;
  }
  L = L / 10.0f;
  *out_loss = L;
}

// ---------------- host ----------------

struct Ptrs {
  const float *f, *emb;
  unsigned short *ePack;
  float *e_sq, *frest, *fhat, *rest, *Mdown, *Mup, *wPack, *bestW;
  int *idxW;
  double *partial;
  float *out0, *out_levels;
  const float *phi_b;
};

template<int PN, int PN2, int NSPLIT, bool LAST>
static void run_scale(const Ptrs& P, int si, int pi, int mup_off, int mdn_off,
                      hipStream_t stream){
  constexpr int N = BB*PN;
  dim3 ag(N/RT, NSPLIT);
  const float* restp = LAST ? P.f : P.rest;
  argmin_mfma<PN, NSPLIT><<<ag, 256, 0, stream>>>(restp, P.ePack, P.e_sq, P.bestW, P.idxW);
  fused_phi<PN, PN2, NSPLIT, LAST><<<BB, 256, 0, stream>>>(
      P.emb, P.bestW, P.idxW, P.Mup + mup_off,
      P.wPack + (size_t)pi*64*196, P.phi_b + (size_t)pi*CC,
      P.f, P.fhat, P.frest, P.out_levels + (size_t)si*NEL, P.out0,
      P.rest, P.Mdown + mdn_off, P.partial, si);
}

extern "C" void kernel_launch(void* const* d_in, const int* in_sizes, int n_in,
                              void* d_out, int out_size, void* d_ws, size_t ws_size,
                              hipStream_t stream) {
  const float* f     = (const float*)d_in[0];
  const float* emb   = (const float*)d_in[1];
  const float* phi_w = (const float*)d_in[2];
  const float* phi_b = (const float*)d_in[3];
  float* out0       = (float*)d_out;
  float* out_loss   = out0 + NEL;
  float* out_levels = out0 + NEL + 1;

  double* partial      = (double*)d_ws;                 // 16
  unsigned short* ePack = (unsigned short*)(partial + 16); // 786432 u16 + 16384 slack (1.57MB)
  float*  e_sq    = (float*)(ePack + 786432 + 16384);   // 4096
  float*  frest   = e_sq + 4096;                        // NEL
  float*  fhat    = frest + NEL;                        // NEL
  float*  rest    = fhat + NEL;                         // NEL (max)
  float*  Mdown   = rest + NEL;                         // 3584
  float*  Mup     = Mdown + 3584;                       // 3584
  float*  wPack   = Mup + 3584;                         // 50176
  float*  bestW   = wPack + 50176;                      // 262144
  int*    idxW    = (int*)(bestW + 262144);             // 262144

  // pi table: exact IEEE-fp64 mirror of np.linspace + argmin(|TICKS - si/9|)
  double q = 1.0/3.0; q = q/4.0;
  double start = q;
  double stop  = 1.0 - q;
  double delta = stop - start;
  double step  = delta/3.0;
  double ticks[4];
  ticks[0] = start;
  ticks[1] = step + start;
  { double t2 = 2.0*step; ticks[2] = t2 + start; }
  ticks[3] = stop;
  int pi_tab[10];
  for (int si = 0; si < 10; si++){
    double x = (double)si / 9.0;
    int bi = 0; double bd = fabs(ticks[0] - x);
    for (int i2 = 1; i2 < 4; i2++){
      double dd = fabs(ticks[i2] - x);
      if (dd < bd) { bd = dd; bi = i2; }
    }
    pi_tab[si] = bi;
  }

  static const int pref[10] = {0,1,3,6,10,16,25,38,56,80};

  setup_all<<<1153, 256, 0, stream>>>(f, emb, phi_w, frest, fhat, rest,
                                      Mdown, Mup, partial, wPack, ePack, e_sq);

  Ptrs P = {f, emb, ePack, e_sq, frest, fhat, rest, Mdown, Mup, wPack, bestW,
            idxW, partial, out0, out_levels, phi_b};

  // scale 9 quantizes f itself (reference: rest = f), so si=8 needs no downsample (PN2=0)
  run_scale< 1,  2, 32, false>(P, 0, pi_tab[0], pref[0]*32, pref[1]*32, stream);
  run_scale< 2,  3, 32, false>(P, 1, pi_tab[1], pref[1]*32, pref[2]*32, stream);
  run_scale< 3,  4, 32, false>(P, 2, pi_tab[2], pref[2]*32, pref[3]*32, stream);
  run_scale< 4,  6, 32, false>(P, 3, pi_tab[3], pref[3]*32, pref[4]*32, stream);
  run_scale< 6,  9, 16, false>(P, 4, pi_tab[4], pref[4]*32, pref[5]*32, stream);
  run_scale< 9, 13, 16, false>(P, 5, pi_tab[5], pref[5]*32, pref[6]*32, stream);
  run_scale<13, 18,  8, false>(P, 6, pi_tab[6], pref[6]*32, pref[7]*32, stream);
  run_scale<18, 24,  8, false>(P, 7, pi_tab[7], pref[7]*32, pref[8]*32, stream);
  run_scale<24,  0,  8, false>(P, 8, pi_tab[8], pref[8]*32, 0,          stream);
  run_scale<32,  0,  8, true >(P, 9, pi_tab[9], pref[9]*32, 0,          stream);

  finalize<<<1, 1, 0, stream>>>(partial, out_loss);
}

// Round 9
// 983.093 us; speedup vs baseline: 1.0463x; 1.0299x over previous
//
#include <hip/hip_runtime.h>
#include <math.h>

#define BB 1024
#define CC 64
#define HH 32
#define VV 4096
#define NEL (BB*CC*HH)   // 2097152

#define RT 128        // rows per argmin block

typedef __attribute__((ext_vector_type(4))) float f32x4;
typedef __attribute__((ext_vector_type(8))) short bf16x8;   // 8 bf16 = 4 VGPRs

// ---------------- setup ----------------

__device__ double dev_cubic(double x){
#pragma clang fp contract(off)
  const double A = -0.75;
  x = fabs(x);
  if (x <= 1.0) return ((A + 2.0)*x - (A + 3.0))*x*x + 1.0;
  if (x < 2.0)  return A*(((x - 5.0)*x + 8.0)*x - 4.0);
  return 0.0;
}

__device__ __constant__ int c_vpatch[10] = {1,2,3,4,6,9,13,18,24,32};
__device__ __constant__ int c_pref[10]   = {0,1,3,6,10,16,25,38,56,80};

// numpy scalar pairwise-8 sum of fl32 squares of 64 contiguous floats
__device__ float np_pairwise8_sq64(const float* a){
#pragma clang fp contract(off)
  float r0 = a[0]*a[0], r1 = a[1]*a[1], r2 = a[2]*a[2], r3 = a[3]*a[3];
  float r4 = a[4]*a[4], r5 = a[5]*a[5], r6 = a[6]*a[6], r7 = a[7]*a[7];
  for (int i = 8; i < 64; i += 8){
    float s0 = a[i+0]*a[i+0]; r0 = r0 + s0;
    float s1 = a[i+1]*a[i+1]; r1 = r1 + s1;
    float s2 = a[i+2]*a[i+2]; r2 = r2 + s2;
    float s3 = a[i+3]*a[i+3]; r3 = r3 + s3;
    float s4 = a[i+4]*a[i+4]; r4 = r4 + s4;
    float s5 = a[i+5]*a[i+5]; r5 = r5 + s5;
    float s6 = a[i+6]*a[i+6]; r6 = r6 + s6;
    float s7 = a[i+7]*a[i+7]; r7 = r7 + s7;
  }
  return ((r0 + r1) + (r2 + r3)) + ((r4 + r5) + (r6 + r7));
}

// ---- exact 3-way bf16 truncation split: a == bf(s1)+bf(s2)+bf(s3) exactly ----
__device__ inline void split3t(float a, unsigned short& s1, unsigned short& s2, unsigned short& s3){
  unsigned u1 = __float_as_uint(a);
  s1 = (unsigned short)(u1 >> 16);
  float f1 = __uint_as_float(u1 & 0xffff0000u);
  float r1 = a - f1;                                  // exact
  unsigned u2 = __float_as_uint(r1);
  s2 = (unsigned short)(u2 >> 16);
  float f2 = __uint_as_float(u2 & 0xffff0000u);
  float r2 = r1 - f2;                                 // exact, <=8 sig bits
  s3 = (unsigned short)(__float_as_uint(r2) >> 16);   // lossless
}

// ---------------- fused setup: init + pack_w + prep_emb + gen_setup ----------
__global__ __launch_bounds__(256) void setup_all(
    const float* __restrict__ f, const float* __restrict__ emb,
    const float* __restrict__ phi_w,
    float* frest, float* fhat, float* rest0,
    float* Mdown, float* Mup,
    float* wPack, unsigned short* ePack, float* e_sq)
{
#pragma clang fp contract(off)
  __shared__ float rows[64][65];     // prep role only (16.6KB)
  int blk = blockIdx.x, t = threadIdx.x;

  if (blk < 1024){
    int b = blk;
    for (int e = t; e < 2048; e += 256){
      float v = f[b*2048 + e];
      frest[b*2048 + e] = v;
      fhat[b*2048 + e] = 0.0f;
    }
    if (t < 64) rest0[b*64 + t] = f[b*2048 + t*32];   // h=0 sample, exact
  } else if (blk < 1088){
    int e0 = (blk - 1024)*784;       // 4*64*196 = 50176 = 64*784
    for (int i = t; i < 784; i += 256){
      int e = e0 + i;
      int pi = e / (64*196);
      int r  = e - pi*64*196;
      int co = r / 196, m = r - co*196;
      float v = 0.0f;
      if (m < 192){
        int ci = m / 3, kh = m - ci*3;
        v = phi_w[(((pi*64 + co)*64 + ci)*3 + kh)*3 + 1];
      }
      wPack[e] = v;
    }
  } else if (blk < 1152){
    int v0 = (blk - 1088)*64;
    for (int e = t; e < 4096; e += 256){
      int vl = e >> 6, c = e & 63;
      rows[vl][c] = emb[(size_t)(v0 + vl)*64 + c];   // coalesced
    }
    __syncthreads();
    if (t < 64){
      int v = v0 + t;
      e_sq[v] = np_pairwise8_sq64(&rows[t][0]);      // exact numpy order
      int vt = v >> 4, col = v & 15;
#pragma unroll
      for (int o = 0; o < 8; o++){
        bf16x8 v1, v2, v3;
#pragma unroll
        for (int jj = 0; jj < 8; jj++){
          unsigned short s1, s2, s3;
          split3t(rows[t][o*8 + jj], s1, s2, s3);
          v1[jj] = (short)s1; v2[jj] = (short)s2; v3[jj] = (short)s3;
        }
        int kk = o >> 2, g = o & 3;
        size_t base = ((size_t)((vt*2 + kk)*3))*512 + (size_t)(g*16 + col)*8;
        *(bf16x8*)&ePack[base       ] = v1;
        *(bf16x8*)&ePack[base +  512] = v2;
        *(bf16x8*)&ePack[base + 1024] = v3;
      }
    }
  } else {
    for (int i = t; i < 3584; i += 256) { Mdown[i] = 0.0f; Mup[i] = 0.0f; }
    __syncthreads();
    if (t < 20) {
      int si = t >> 1; int up = t & 1;
      int pn = c_vpatch[si];
      if (!up) {
        float* M = Mdown + c_pref[si]*32;          // [pn][32], align_corners=True
        for (int o = 0; o < pn; o++){
          double src = (pn == 1) ? 0.0 : (double)(o*(32-1)) / (double)(pn-1);
          double fl = floor(src); double tt = src - fl; int fli = (int)fl;
          for (int k = -1; k <= 2; k++){
            int j = fli + k; j = j < 0 ? 0 : (j > 31 ? 31 : j);
            float w = (float)dev_cubic((double)k - tt);
            M[o*32 + j] = M[o*32 + j] + w;
          }
        }
      } else {
        float* M = Mup + c_pref[si]*32;            // [32][pn], align_corners=False
        for (int o = 0; o < 32; o++){
          double src = ((double)o + 0.5) * (double)pn / 32.0 - 0.5;
          double fl = floor(src); double tt = src - fl; int fli = (int)fl;
          for (int k = -1; k <= 2; k++){
            int j = fli + k; j = j < 0 ? 0 : (j > pn-1 ? pn-1 : j);
            float w = (float)dev_cubic((double)k - tt);
            M[o*pn + j] = M[o*pn + j] + w;
          }
        }
      }
    }
  }
}

// ---------------- argmin via MFMA bf16x3 (6-product fp32 emulation) ----------------
// Round-6 form VERBATIM (measured 91.2us, VGPR 72, no spill).

template<int PN, int NSPLIT>
__global__ __launch_bounds__(256,2) void argmin_mfma(const float* __restrict__ rest,
    const unsigned short* __restrict__ ePack, const float* __restrict__ e_sq,
    float* __restrict__ bestW, int* __restrict__ idxW)
{
#pragma clang fp contract(off)
  constexpr int VSPL = VV / NSPLIT;     // codes per block (>=128)
  constexpr int NVT  = VSPL / 16;       // 16-code tiles per block (>=8, even)
  constexpr int CH   = 2;               // tiles per staged round (12KB)
  constexpr int NR   = NVT / CH;
  static_assert(NVT % CH == 0, "NVT must be multiple of CH");

  __shared__ __align__(16) unsigned short eS[2][CH*6*512];   // 2 x 12KB
  __shared__ float esL[VSPL];
  __shared__ float sR[RT];

  const int n0    = blockIdx.x * RT;
  const int split = blockIdx.y;
  const int v0    = split * VSPL;
  const int t     = threadIdx.x;
  const int lane  = t & 63;
  const int w     = t >> 6;
  const int m     = lane & 15;
  const int g     = lane >> 4;

  // wave w owns chunks [w*3, w*3+3) of each 12-chunk round
  const unsigned short* gW = ePack + (size_t)(v0 >> 4)*3072
                           + (size_t)w*3*512 + (size_t)lane*8;
  bf16x8 st[3];
#pragma unroll
  for (int c = 0; c < 3; c++) st[c] = *(const bf16x8*)(gW + c*512);

  for (int e = t; e < VSPL; e += 256) esL[e] = e_sq[v0 + e];

  // A-fragment direct gather + in-register split
  bf16x8 aF[2][2][3];                 // [rt][kk][split]
  const int rt0 = w*2;
#pragma unroll
  for (int r2 = 0; r2 < 2; r2++){
    int n = n0 + (rt0 + r2)*16 + m;
    int b = n / PN, p = n % PN;       // compile-time divisor
    const float* rb = rest + (size_t)b*CC*PN + p;
#pragma unroll
    for (int kk = 0; kk < 2; kk++){
#pragma unroll
      for (int jj = 0; jj < 8; jj++){
        int c = kk*32 + g*8 + jj;
        float a = rb[(size_t)c*PN];
        unsigned short s1, s2, s3;
        split3t(a, s1, s2, s3);
        aF[r2][kk][0][jj] = (short)s1;
        aF[r2][kk][1][jj] = (short)s2;
        aF[r2][kk][2][jj] = (short)s3;
      }
    }
  }

  // sR: exact numpy pairwise-8 row norm, straight from global
  if (t < RT){
    int n = n0 + t;
    int b = n / PN, p = n % PN;
    const float* rb = rest + (size_t)b*CC*PN + p;
    float a0 = rb[0];              float r0 = a0*a0;
    float a1 = rb[(size_t)1*PN];   float r1 = a1*a1;
    float a2 = rb[(size_t)2*PN];   float r2 = a2*a2;
    float a3 = rb[(size_t)3*PN];   float r3 = a3*a3;
    float a4 = rb[(size_t)4*PN];   float r4 = a4*a4;
    float a5 = rb[(size_t)5*PN];   float r5 = a5*a5;
    float a6 = rb[(size_t)6*PN];   float r6 = a6*a6;
    float a7 = rb[(size_t)7*PN];   float r7 = a7*a7;
    for (int i = 8; i < 64; i += 8){
      float b0 = rb[(size_t)(i+0)*PN]; float s0 = b0*b0; r0 = r0 + s0;
      float b1 = rb[(size_t)(i+1)*PN]; float s1 = b1*b1; r1 = r1 + s1;
      float b2 = rb[(size_t)(i+2)*PN]; float s2 = b2*b2; r2 = r2 + s2;
      float b3 = rb[(size_t)(i+3)*PN]; float s3 = b3*b3; r3 = r3 + s3;
      float b4 = rb[(size_t)(i+4)*PN]; float s4 = b4*b4; r4 = r4 + s4;
      float b5 = rb[(size_t)(i+5)*PN]; float s5 = b5*b5; r5 = r5 + s5;
      float b6 = rb[(size_t)(i+6)*PN]; float s6 = b6*b6; r6 = r6 + s6;
      float b7 = rb[(size_t)(i+7)*PN]; float s7 = b7*b7; r7 = r7 + s7;
    }
    sR[t] = ((r0 + r1) + (r2 + r3)) + ((r4 + r5) + (r6 + r7));
  }

  // stage round 0
#pragma unroll
  for (int c = 0; c < 3; c++)
    *(bf16x8*)&eS[0][(w*3 + c)*512 + (size_t)lane*8] = st[c];
  __syncthreads();

  f32x4 sRl[2];
  sRl[0] = *(const f32x4*)&sR[(rt0+0)*16 + g*4];
  sRl[1] = *(const f32x4*)&sR[(rt0+1)*16 + g*4];

  float best[2][4]; int bidx[2][4];
#pragma unroll
  for (int r2 = 0; r2 < 2; r2++)
#pragma unroll
    for (int rg = 0; rg < 4; rg++){ best[r2][rg] = 3.0e38f; bidx[r2][rg] = 0; }

  // per-acc MFMA order + epilogue identical to verified round-3 kernel
#define CTILE(eF, VT) do { \
    f32x4 acc0 = {0.f,0.f,0.f,0.f}; \
    f32x4 acc1 = {0.f,0.f,0.f,0.f}; \
    __builtin_amdgcn_s_setprio(1); \
    acc0 = __builtin_amdgcn_mfma_f32_16x16x32_bf16(aF[0][0][0], eF[0], acc0, 0,0,0); \
    acc1 = __builtin_amdgcn_mfma_f32_16x16x32_bf16(aF[1][0][0], eF[0], acc1, 0,0,0); \
    acc0 = __builtin_amdgcn_mfma_f32_16x16x32_bf16(aF[0][0][0], eF[1], acc0, 0,0,0); \
    acc1 = __builtin_amdgcn_mfma_f32_16x16x32_bf16(aF[1][0][0], eF[1], acc1, 0,0,0); \
    acc0 = __builtin_amdgcn_mfma_f32_16x16x32_bf16(aF[0][0][1], eF[0], acc0, 0,0,0); \
    acc1 = __builtin_amdgcn_mfma_f32_16x16x32_bf16(aF[1][0][1], eF[0], acc1, 0,0,0); \
    acc0 = __builtin_amdgcn_mfma_f32_16x16x32_bf16(aF[0][0][1], eF[1], acc0, 0,0,0); \
    acc1 = __builtin_amdgcn_mfma_f32_16x16x32_bf16(aF[1][0][1], eF[1], acc1, 0,0,0); \
    acc0 = __builtin_amdgcn_mfma_f32_16x16x32_bf16(aF[0][0][0], eF[2], acc0, 0,0,0); \
    acc1 = __builtin_amdgcn_mfma_f32_16x16x32_bf16(aF[1][0][0], eF[2], acc1, 0,0,0); \
    acc0 = __builtin_amdgcn_mfma_f32_16x16x32_bf16(aF[0][0][2], eF[0], acc0, 0,0,0); \
    acc1 = __builtin_amdgcn_mfma_f32_16x16x32_bf16(aF[1][0][2], eF[0], acc1, 0,0,0); \
    acc0 = __builtin_amdgcn_mfma_f32_16x16x32_bf16(aF[0][1][0], eF[3], acc0, 0,0,0); \
    acc1 = __builtin_amdgcn_mfma_f32_16x16x32_bf16(aF[1][1][0], eF[3], acc1, 0,0,0); \
    acc0 = __builtin_amdgcn_mfma_f32_16x16x32_bf16(aF[0][1][0], eF[4], acc0, 0,0,0); \
    acc1 = __builtin_amdgcn_mfma_f32_16x16x32_bf16(aF[1][1][0], eF[4], acc1, 0,0,0); \
    acc0 = __builtin_amdgcn_mfma_f32_16x16x32_bf16(aF[0][1][1], eF[3], acc0, 0,0,0); \
    acc1 = __builtin_amdgcn_mfma_f32_16x16x32_bf16(aF[1][1][1], eF[3], acc1, 0,0,0); \
    acc0 = __builtin_amdgcn_mfma_f32_16x16x32_bf16(aF[0][1][1], eF[4], acc0, 0,0,0); \
    acc1 = __builtin_amdgcn_mfma_f32_16x16x32_bf16(aF[1][1][1], eF[4], acc1, 0,0,0); \
    acc0 = __builtin_amdgcn_mfma_f32_16x16x32_bf16(aF[0][1][0], eF[5], acc0, 0,0,0); \
    acc1 = __builtin_amdgcn_mfma_f32_16x16x32_bf16(aF[1][1][0], eF[5], acc1, 0,0,0); \
    acc0 = __builtin_amdgcn_mfma_f32_16x16x32_bf16(aF[0][1][2], eF[3], acc0, 0,0,0); \
    acc1 = __builtin_amdgcn_mfma_f32_16x16x32_bf16(aF[1][1][2], eF[3], acc1, 0,0,0); \
    __builtin_amdgcn_s_setprio(0); \
    int vt_ = (VT); \
    float es = esL[vt_*16 + m]; \
    int codeBase = v0 + vt_*16 + m; \
    _Pragma("unroll") \
    for (int rg = 0; rg < 4; rg++){ \
      float t1a = sRl[0][rg] + es;                 /* fl(R + e_sq) */ \
      float da  = fmaf(-2.0f, acc0[rg], t1a);      /* == fl(t1 - 2*dot) */ \
      if (da < best[0][rg]) { best[0][rg] = da; bidx[0][rg] = codeBase; } \
      float t1b = sRl[1][rg] + es; \
      float db  = fmaf(-2.0f, acc1[rg], t1b); \
      if (db < best[1][rg]) { best[1][rg] = db; bidx[1][rg] = codeBase; } \
    } } while(0)

  int cur = 0;
  for (int r = 0; r < NR; r++){
    if (r + 1 < NR){
      const unsigned short* gR = gW + (size_t)(r+1)*CH*6*512;
#pragma unroll
      for (int c = 0; c < 3; c++) st[c] = *(const bf16x8*)(gR + c*512);
    }
#pragma unroll
    for (int q = 0; q < CH; q++){
      bf16x8 eF[6];
#pragma unroll
      for (int k = 0; k < 6; k++)
        eF[k] = *(const bf16x8*)&eS[cur][(q*6 + k)*512 + (size_t)lane*8];
      CTILE(eF, r*CH + q);
    }
    if (r + 1 < NR){
#pragma unroll
      for (int c = 0; c < 3; c++)
        *(bf16x8*)&eS[cur ^ 1][(w*3 + c)*512 + (size_t)lane*8] = st[c];
    }
    __syncthreads();
    cur ^= 1;
  }
#undef CTILE

  // per-row reduce over the 16 lanes sharing (lane>>4); first-min (smaller code on tie)
#pragma unroll
  for (int r2 = 0; r2 < 2; r2++)
#pragma unroll
    for (int rg = 0; rg < 4; rg++){
      float v = best[r2][rg]; int ix = bidx[r2][rg];
      for (int off = 8; off; off >>= 1){
        float ov = __shfl_down(v, off, 16);
        int   oi = __shfl_down(ix, off, 16);
        if (ov < v || (ov == v && oi < ix)) { v = ov; ix = oi; }
      }
      if ((lane & 15) == 0){
        int n = n0 + (rt0 + r2)*16 + (lane>>4)*4 + rg;
        bestW[n*NSPLIT + split] = v;
        idxW [n*NSPLIT + split] = ix;
      }
    }
}

// ---------------- fused split-reduce + upsample/gather + Phi + next-scale downsample ----------------
// Change vs round 8: the 1024-way same-address f64 atomicAdd is replaced by a
// per-block slot store (blkSum[si*1024+b]); finalize does the reduction.

template<int PN, int PN2, int NSPLIT, bool LAST>
__global__ __launch_bounds__(256) void fused_phi(
    const float* __restrict__ emb,
    const float* __restrict__ bestW, const int* __restrict__ idxW,
    const float* __restrict__ Mup, const float* __restrict__ wP,
    const float* __restrict__ bias, const float* __restrict__ f,
    float* fhat, float* frest, float* levels_out, float* final_out,
    float* rest_next, const float* __restrict__ Mdown_next,
    double* blkSum, int si)
{
#pragma clang fp contract(off)
  __shared__ float huP[64][36];   // [ci][1+h], zero borders at 0 and 33
  __shared__ union { float hE[24*64]; float frL[64*33]; } u;   // phase-disjoint
  __shared__ float mUp[32*25];    // [o][p], stride PN+1 (<=25)
  __shared__ float mDn[32*33];    // [p][h], stride 33
  __shared__ int idxL[32];
  __shared__ double red[4];
  int b = blockIdx.x, t = threadIdx.x;

  // fold of argmin_reduce: cross-split first-min (splits ascending, strict <)
  if (t < PN){
    int base = (b*PN + t)*NSPLIT;
    float v = bestW[base]; int ix = idxW[base];
#pragma unroll
    for (int s = 1; s < NSPLIT; s++){
      float ov = bestW[base + s];
      if (ov < v) { v = ov; ix = idxW[base + s]; }
    }
    idxL[t] = ix;
  }
  if (t < 64){ huP[t][0] = 0.0f; huP[t][33] = 0.0f; huP[t][34] = 0.0f; huP[t][35] = 0.0f; }
  if (PN2 > 0){
    for (int e = t; e < PN2*32; e += 256){
      int p = e >> 5, h = e & 31;
      mDn[p*33 + h] = Mdown_next[e];
    }
  }
  if (!LAST){
    for (int e = t; e < 32*PN; e += 256){
      int o = e / PN, p = e - o*PN;
      mUp[o*(PN+1) + p] = Mup[e];
    }
  }
  __syncthreads();

  if (!LAST){
    for (int e = t; e < PN*64; e += 256){
      int p = e >> 6, c = e & 63;
      u.hE[p*64 + c] = emb[idxL[p]*64 + c];
    }
    __syncthreads();
    for (int e = t; e < 2048; e += 256){
      int c = e >> 5, o = e & 31;
      const float* mr = &mUp[o*(PN+1)];
      float s = 0.0f;
#pragma unroll
      for (int p = 0; p < PN; p++){ float pr = mr[p]*u.hE[p*64 + c]; s = s + pr; }
      huP[c][1 + o] = s;
    }
  } else {
    for (int e = t; e < 2048; e += 256){
      int h = e >> 6, c = e & 63;
      huP[c][1 + h] = emb[idxL[h]*64 + c];
    }
  }
  __syncthreads();   // hE dead after this point

  // conv3 along H; weights direct from global (L2-hot, broadcast across the
  // 4 threads sharing co); huP via vectorized LDS reads
  int co = t >> 2, h0 = (t & 3) * 8;
  float y[8];
#pragma unroll
  for (int uu = 0; uu < 8; uu++) y[uu] = 0.0f;
  for (int ci4 = 0; ci4 < 64; ci4 += 4){
    float4 wa = *(const float4*)&wP[co*196 + ci4*3];
    float4 wb = *(const float4*)&wP[co*196 + ci4*3 + 4];
    float4 wc = *(const float4*)&wP[co*196 + ci4*3 + 8];
    float wv[12] = {wa.x,wa.y,wa.z,wa.w, wb.x,wb.y,wb.z,wb.w, wc.x,wc.y,wc.z,wc.w};
#pragma unroll
    for (int q = 0; q < 4; q++){
      int ci = ci4 + q;
      float4 xa = *(const float4*)&huP[ci][h0];
      float4 xb = *(const float4*)&huP[ci][h0 + 4];
      float2 xc = *(const float2*)&huP[ci][h0 + 8];
      float x[10] = {xa.x,xa.y,xa.z,xa.w, xb.x,xb.y,xb.z,xb.w, xc.x,xc.y};
      float w0 = wv[q*3], w1 = wv[q*3+1], w2 = wv[q*3+2];
#pragma unroll
      for (int uu = 0; uu < 8; uu++){
        y[uu] = fmaf(w0, x[uu],   y[uu]);
        y[uu] = fmaf(w1, x[uu+1], y[uu]);
        y[uu] = fmaf(w2, x[uu+2], y[uu]);
      }
    }
  }

  float bb = bias[co];
  double lsum = 0.0;
  int base = b*2048 + co*32 + h0;
#pragma unroll
  for (int uu = 0; uu < 8; uu++){
    float yv = y[uu] + bb;                           // conv + bias (after)
    float hp = 0.5f*huP[co][1 + h0 + uu] + 0.5f*yv;  // h*(1-r) + y*r, r=0.5
    float fh = fhat[base+uu] + hp;
    fhat[base+uu] = fh;
    float fr = frest[base+uu] - hp;
    frest[base+uu] = fr;
    u.frL[co*33 + h0 + uu] = fr;
    float fv = f[base+uu];
    float dv = fh - fv;
    lsum += (double)dv*(double)dv;
    levels_out[base+uu] = fh;
    if (LAST) final_out[base+uu] = dv + fv;    // straight-through: fl(fl(fh-f)+f)
  }
  for (int off = 32; off; off >>= 1) lsum += __shfl_down(lsum, off);
  if ((t & 63) == 0) red[t >> 6] = lsum;
  __syncthreads();

  if (PN2 > 0){
    for (int e = t; e < 64*PN2; e += 256){
      int c = e / PN2, p = e - c*PN2;
      const float* mr = &mDn[p*33];
      float s = 0.0f;
#pragma unroll
      for (int h = 0; h < 32; h++){ float pr = mr[h]*u.frL[c*33 + h]; s = s + pr; }
      rest_next[(b*64 + c)*PN2 + p] = s;
    }
  }
  if (t == 0) blkSum[(size_t)si*BB + b] = red[0] + red[1] + red[2] + red[3];
}

// tree reduction of per-block sums (deterministic; double headroom makes
// order-vs-atomic differences ~1e-16 rel, far below final fp32 rounding)
__global__ __launch_bounds__(256) void finalize(const double* __restrict__ blkSum,
                                                float* out_loss){
#pragma clang fp contract(off)
  __shared__ double wsum[4];
  __shared__ float Ls[10];
  int t = threadIdx.x;
  for (int si = 0; si < 10; si++){
    const double* bs = blkSum + (size_t)si*BB;
    double s = 0.0;
#pragma unroll
    for (int i = 0; i < 4; i++) s += bs[t*4 + i];
    for (int off = 32; off; off >>= 1) s += __shfl_down(s, off);
    if ((t & 63) == 0) wsum[t >> 6] = s;
    __syncthreads();
    if (t == 0){
      double tot = (wsum[0] + wsum[1]) + (wsum[2] + wsum[3]);
      Ls[si] = (float)(tot / (double)NEL);
    }
    __syncthreads();
  }
  if (t == 0){
    float L = 0.0f;
    for (int si = 0; si < 10; si++){
      float m = Ls[si];
      float t1 = 0.25f * m;
      L = L + t1;
      L = L + m;
    }
    L = L / 10.0f;
    *out_loss = L;
  }
}

// ---------------- host ----------------

struct Ptrs {
  const float *f, *emb;
  unsigned short *ePack;
  float *e_sq, *frest, *fhat, *rest, *Mdown, *Mup, *wPack, *bestW;
  int *idxW;
  double *blkSum;
  float *out0, *out_levels;
  const float *phi_b;
};

template<int PN, int PN2, int NSPLIT, bool LAST>
static void run_scale(const Ptrs& P, int si, int pi, int mup_off, int mdn_off,
                      hipStream_t stream){
  constexpr int N = BB*PN;
  dim3 ag(N/RT, NSPLIT);
  const float* restp = LAST ? P.f : P.rest;
  argmin_mfma<PN, NSPLIT><<<ag, 256, 0, stream>>>(restp, P.ePack, P.e_sq, P.bestW, P.idxW);
  fused_phi<PN, PN2, NSPLIT, LAST><<<BB, 256, 0, stream>>>(
      P.emb, P.bestW, P.idxW, P.Mup + mup_off,
      P.wPack + (size_t)pi*64*196, P.phi_b + (size_t)pi*CC,
      P.f, P.fhat, P.frest, P.out_levels + (size_t)si*NEL, P.out0,
      P.rest, P.Mdown + mdn_off, P.blkSum, si);
}

extern "C" void kernel_launch(void* const* d_in, const int* in_sizes, int n_in,
                              void* d_out, int out_size, void* d_ws, size_t ws_size,
                              hipStream_t stream) {
  const float* f     = (const float*)d_in[0];
  const float* emb   = (const float*)d_in[1];
  const float* phi_w = (const float*)d_in[2];
  const float* phi_b = (const float*)d_in[3];
  float* out0       = (float*)d_out;
  float* out_loss   = out0 + NEL;
  float* out_levels = out0 + NEL + 1;

  double* blkSum       = (double*)d_ws;                 // 10*1024
  unsigned short* ePack = (unsigned short*)(blkSum + 10240); // 786432 u16 + 16384 slack
  float*  e_sq    = (float*)(ePack + 786432 + 16384);   // 4096
  float*  frest   = e_sq + 4096;                        // NEL
  float*  fhat    = frest + NEL;                        // NEL
  float*  rest    = fhat + NEL;                         // NEL (max)
  float*  Mdown   = rest + NEL;                         // 3584
  float*  Mup     = Mdown + 3584;                       // 3584
  float*  wPack   = Mup + 3584;                         // 50176
  float*  bestW   = wPack + 50176;                      // 262144
  int*    idxW    = (int*)(bestW + 262144);             // 262144

  // pi table: exact IEEE-fp64 mirror of np.linspace + argmin(|TICKS - si/9|)
  double q = 1.0/3.0; q = q/4.0;
  double start = q;
  double stop  = 1.0 - q;
  double delta = stop - start;
  double step  = delta/3.0;
  double ticks[4];
  ticks[0] = start;
  ticks[1] = step + start;
  { double t2 = 2.0*step; ticks[2] = t2 + start; }
  ticks[3] = stop;
  int pi_tab[10];
  for (int si = 0; si < 10; si++){
    double x = (double)si / 9.0;
    int bi = 0; double bd = fabs(ticks[0] - x);
    for (int i2 = 1; i2 < 4; i2++){
      double dd = fabs(ticks[i2] - x);
      if (dd < bd) { bd = dd; bi = i2; }
    }
    pi_tab[si] = bi;
  }

  static const int pref[10] = {0,1,3,6,10,16,25,38,56,80};

  setup_all<<<1153, 256, 0, stream>>>(f, emb, phi_w, frest, fhat, rest,
                                      Mdown, Mup, wPack, ePack, e_sq);

  Ptrs P = {f, emb, ePack, e_sq, frest, fhat, rest, Mdown, Mup, wPack, bestW,
            idxW, blkSum, out0, out_levels, phi_b};

  // scale 9 quantizes f itself (reference: rest = f), so si=8 needs no downsample (PN2=0)
  run_scale< 1,  2, 32, false>(P, 0, pi_tab[0], pref[0]*32, pref[1]*32, stream);
  run_scale< 2,  3, 32, false>(P, 1, pi_tab[1], pref[1]*32, pref[2]*32, stream);
  run_scale< 3,  4, 32, false>(P, 2, pi_tab[2], pref[2]*32, pref[3]*32, stream);
  run_scale< 4,  6, 32, false>(P, 3, pi_tab[3], pref[3]*32, pref[4]*32, stream);
  run_scale< 6,  9, 16, false>(P, 4, pi_tab[4], pref[4]*32, pref[5]*32, stream);
  run_scale< 9, 13, 16, false>(P, 5, pi_tab[5], pref[5]*32, pref[6]*32, stream);
  run_scale<13, 18,  8, false>(P, 6, pi_tab[6], pref[6]*32, pref[7]*32, stream);
  run_scale<18, 24,  8, false>(P, 7, pi_tab[7], pref[7]*32, pref[8]*32, stream);
  run_scale<24,  0,  8, false>(P, 8, pi_tab[8], pref[8]*32, 0,          stream);
  run_scale<32,  0,  8, true >(P, 9, pi_tab[9], pref[9]*32, 0,          stream);

  finalize<<<1, 256, 0, stream>>>(blkSum, out_loss);
}